// Round 11
// baseline (1065.422 us; speedup 1.0000x reference)
//
#include <hip/hip_runtime.h>
#include <hip/hip_bf16.h>

#define IN_FEATS 768
#define PART_CHUNK 8192
#define SRC_BITS 17
#define SRC_MASK 0x1FFFF

// DIAGNOSTIC ROUND: per-kernel in-kernel reps so each crosses the ~183us
// top-5 visibility threshold and reports counters.
#define REPS_P  12   // partition
#define REPS_F  16   // csr_finalize
#define REPS_G  4    // gemm1
#define REPS_A1 6    // agg1

typedef __attribute__((ext_vector_type(8))) short short8v;
typedef __attribute__((ext_vector_type(4))) float f32x4;

__device__ __forceinline__ unsigned short f2bf(float f) {
    union { float f; unsigned int u; } c; c.f = f;
    unsigned int r = (c.u + 0x7FFFu + ((c.u >> 16) & 1u)) >> 16;  // RNE
    return (unsigned short)r;
}
__device__ __forceinline__ float bflo(unsigned int v) {
    union { unsigned int u; float f; } c; c.u = v << 16; return c.f;
}
__device__ __forceinline__ float bfhi(unsigned int v) {
    union { unsigned int u; float f; } c; c.u = v & 0xFFFF0000u; return c.f;
}
__device__ __forceinline__ short8v pack8(float4 p, float4 q) {
    short8v r;
    r[0] = (short)f2bf(p.x); r[1] = (short)f2bf(p.y);
    r[2] = (short)f2bf(p.z); r[3] = (short)f2bf(p.w);
    r[4] = (short)f2bf(q.x); r[5] = (short)f2bf(q.y);
    r[6] = (short)f2bf(q.z); r[7] = (short)f2bf(q.w);
    return r;
}

// ---------------------------------------------------------------------------
// gemm1 v3 (swizzled LDS) — DIAGNOSTIC x4 reps.
// ---------------------------------------------------------------------------
__global__ __launch_bounds__(256) void gemm1_kernel(
    const float* __restrict__ x,
    const float* __restrict__ Wn,
    const float* __restrict__ Ws,
    const float* __restrict__ b1,
    unsigned short* __restrict__ hn1b,
    float* __restrict__ hs1,
    int N)
{
    __shared__ unsigned short As[2][64][64];
    __shared__ unsigned short Bs[2][64][64];

    const int tid  = threadIdx.x;
    const int lrow = tid >> 2;
    const int lk16 = (tid & 3) * 16;
    const int row0 = blockIdx.x * 64;

    const int  grow   = row0 + lrow;
    const bool rvalid = (grow < N);
    const float* xrow = x + (size_t)(rvalid ? grow : (N - 1)) * IN_FEATS;
    const float* wrow = (lrow < 32) ? (Wn + (size_t)lrow * IN_FEATS)
                                    : (Ws + (size_t)(lrow - 32) * IN_FEATS);

    const int w    = tid >> 6;
    const int l    = tid & 63;
    const int lr16 = l & 15;
    const int lk   = (l >> 4) * 8;

    const int sws  = (lrow & 7) << 3;
    const int ra   = w * 16 + lr16;
    const int swa  = (ra & 7) << 3;

    for (int rep = 0; rep < REPS_G; ++rep) {
        asm volatile("" ::: "memory");

        f32x4 acc[4];
#pragma unroll
        for (int ct = 0; ct < 4; ++ct) acc[ct] = (f32x4){0.f, 0.f, 0.f, 0.f};

        float4 a0, a1, a2, a3, w0, w1, w2, w3;
        a0 = *(const float4*)(xrow + lk16 + 0);
        a1 = *(const float4*)(xrow + lk16 + 4);
        a2 = *(const float4*)(xrow + lk16 + 8);
        a3 = *(const float4*)(xrow + lk16 + 12);
        w0 = *(const float4*)(wrow + lk16 + 0);
        w1 = *(const float4*)(wrow + lk16 + 4);
        w2 = *(const float4*)(wrow + lk16 + 8);
        w3 = *(const float4*)(wrow + lk16 + 12);

        const int NSTEP = IN_FEATS / 64;
        for (int step = 0; step < NSTEP; ++step) {
            const int buf = step & 1;
            *(short8v*)&As[buf][lrow][(lk16 + 0) ^ sws] = pack8(a0, a1);
            *(short8v*)&As[buf][lrow][(lk16 + 8) ^ sws] = pack8(a2, a3);
            *(short8v*)&Bs[buf][lrow][(lk16 + 0) ^ sws] = pack8(w0, w1);
            *(short8v*)&Bs[buf][lrow][(lk16 + 8) ^ sws] = pack8(w2, w3);
            __syncthreads();

            if (step + 1 < NSTEP) {
                const int k0 = (step + 1) * 64;
                a0 = *(const float4*)(xrow + k0 + lk16 + 0);
                a1 = *(const float4*)(xrow + k0 + lk16 + 4);
                a2 = *(const float4*)(xrow + k0 + lk16 + 8);
                a3 = *(const float4*)(xrow + k0 + lk16 + 12);
                w0 = *(const float4*)(wrow + k0 + lk16 + 0);
                w1 = *(const float4*)(wrow + k0 + lk16 + 4);
                w2 = *(const float4*)(wrow + k0 + lk16 + 8);
                w3 = *(const float4*)(wrow + k0 + lk16 + 12);
            }

            short8v af0 = *(const short8v*)&As[buf][ra][(lk +  0) ^ swa];
            short8v af1 = *(const short8v*)&As[buf][ra][(lk + 32) ^ swa];
#pragma unroll
            for (int ct = 0; ct < 4; ++ct) {
                const int rb  = ct * 16 + lr16;
                const int swb = (rb & 7) << 3;
                short8v bf0 = *(const short8v*)&Bs[buf][rb][(lk +  0) ^ swb];
                acc[ct] = __builtin_amdgcn_mfma_f32_16x16x32_bf16(af0, bf0, acc[ct], 0, 0, 0);
            }
#pragma unroll
            for (int ct = 0; ct < 4; ++ct) {
                const int rb  = ct * 16 + lr16;
                const int swb = (rb & 7) << 3;
                short8v bf1 = *(const short8v*)&Bs[buf][rb][(lk + 32) ^ swb];
                acc[ct] = __builtin_amdgcn_mfma_f32_16x16x32_bf16(af1, bf1, acc[ct], 0, 0, 0);
            }
        }

        const int rbase = row0 + w * 16 + (l >> 4) * 4;
#pragma unroll
        for (int ct = 0; ct < 4; ++ct) {
            const int ncol = ct * 16 + lr16;
            if (ncol < 32) {
#pragma unroll
                for (int j = 0; j < 4; ++j) {
                    const int r = rbase + j;
                    if (r < N) hn1b[(size_t)r * 32 + ncol] = f2bf(acc[ct][j]);
                }
            } else {
                const int c = ncol - 32;
                const float bias = b1[c];
#pragma unroll
                for (int j = 0; j < 4; ++j) {
                    const int r = rbase + j;
                    if (r < N) hs1[(size_t)r * 32 + c] = acc[ct][j] + bias;
                }
            }
        }
        __syncthreads();
    }
}

// ---------------------------------------------------------------------------
// init REPS_P cursor sets: bcursor[r*512 + b] = b*CAP
// ---------------------------------------------------------------------------
__global__ __launch_bounds__(512) void init_cursor_kernel(
    int* __restrict__ bcursor, int NB, int CAP)
{
    const int t = threadIdx.x;
    for (int r = 0; r < REPS_P; ++r)
        if (t < NB) bcursor[r * 512 + t] = t * CAP;
}

// ---------------------------------------------------------------------------
// partition — DIAGNOSTIC x12 reps. Reps 0..10 -> scratch (own cursor set),
// final rep -> real packed. Final state bit-identical to single-pass.
// PART_CHUNK back to 8192 (A/B vs round-8's 4096: partial-line write amp).
// ---------------------------------------------------------------------------
__global__ __launch_bounds__(256) void partition_kernel(
    const int* __restrict__ src, const int* __restrict__ dst,
    int* __restrict__ bcursor, unsigned int* __restrict__ packed,
    unsigned int* __restrict__ packed_scratch,
    int NB, int E, int CAP)
{
    __shared__ int hcnt[512];
    __shared__ int hbase[512];
    const int t = threadIdx.x;

    const int start = blockIdx.x * PART_CHUNK;
    const int end   = min(start + PART_CHUNK, E);
    const int vend  = start + ((end - start) & ~3);

    for (int rep = 0; rep < REPS_P; ++rep) {
        asm volatile("" ::: "memory");
        int* bcur = bcursor + rep * 512;
        unsigned int* dest = (rep == REPS_P - 1) ? packed : packed_scratch;

        for (int i = t; i < NB; i += 256) hcnt[i] = 0;
        __syncthreads();

        for (int i = start + t * 4; i + 3 < end; i += 1024) {
            const int4 d4 = *(const int4*)&dst[i];
            atomicAdd(&hcnt[d4.x >> 8], 1);
            atomicAdd(&hcnt[d4.y >> 8], 1);
            atomicAdd(&hcnt[d4.z >> 8], 1);
            atomicAdd(&hcnt[d4.w >> 8], 1);
        }
        for (int i = vend + t; i < end; i += 256)
            atomicAdd(&hcnt[dst[i] >> 8], 1);
        __syncthreads();

        for (int i = t; i < NB; i += 256) {
            const int c = hcnt[i];
            hbase[i] = c ? atomicAdd(&bcur[i], c) : 0;
            hcnt[i] = 0;
        }
        __syncthreads();

        for (int i = start + t * 4; i + 3 < end; i += 1024) {
            const int4 d4 = *(const int4*)&dst[i];
            const int4 s4 = *(const int4*)&src[i];
            {
                const int b = d4.x >> 8;
                const int p = hbase[b] + atomicAdd(&hcnt[b], 1);
                if (p < (b + 1) * CAP) dest[p] = ((unsigned int)(d4.x & 255) << SRC_BITS) | (unsigned int)s4.x;
            }
            {
                const int b = d4.y >> 8;
                const int p = hbase[b] + atomicAdd(&hcnt[b], 1);
                if (p < (b + 1) * CAP) dest[p] = ((unsigned int)(d4.y & 255) << SRC_BITS) | (unsigned int)s4.y;
            }
            {
                const int b = d4.z >> 8;
                const int p = hbase[b] + atomicAdd(&hcnt[b], 1);
                if (p < (b + 1) * CAP) dest[p] = ((unsigned int)(d4.z & 255) << SRC_BITS) | (unsigned int)s4.z;
            }
            {
                const int b = d4.w >> 8;
                const int p = hbase[b] + atomicAdd(&hcnt[b], 1);
                if (p < (b + 1) * CAP) dest[p] = ((unsigned int)(d4.w & 255) << SRC_BITS) | (unsigned int)s4.w;
            }
        }
        for (int i = vend + t; i < end; i += 256) {
            const int d = dst[i];
            const int b = d >> 8;
            const int p = hbase[b] + atomicAdd(&hcnt[b], 1);
            if (p < (b + 1) * CAP) dest[p] = ((unsigned int)(d & 255) << SRC_BITS) | (unsigned int)src[i];
        }
        __syncthreads();
    }
}

// ---------------------------------------------------------------------------
// csr_finalize — DIAGNOSTIC x16 reps (idempotent: block-exclusive window,
// fully rewritten each rep).
// ---------------------------------------------------------------------------
__global__ __launch_bounds__(1024) void csr_finalize_kernel(
    const unsigned int* __restrict__ packed, const int* __restrict__ bcursor,
    int* __restrict__ rowstart, int* __restrict__ rowcnt,
    int* __restrict__ edge_src, int N, int CAP)
{
    __shared__ int cnt[256];
    __shared__ int sdata[256];
    __shared__ int cur[256];
    const int b = blockIdx.x;
    const int t = threadIdx.x;
    const int base = b * CAP;
    const int endp = min(bcursor[b], base + CAP);

    for (int rep = 0; rep < REPS_F; ++rep) {
        asm volatile("" ::: "memory");

        if (t < 256) cnt[t] = 0;
        __syncthreads();
        for (int i = base + t; i < endp; i += 1024)
            atomicAdd(&cnt[packed[i] >> SRC_BITS], 1);
        __syncthreads();

        if (t < 256) sdata[t] = cnt[t];
        __syncthreads();
        for (int off = 1; off < 256; off <<= 1) {
            const int add = (t < 256 && t >= off) ? sdata[t - off] : 0;
            __syncthreads();
            if (t < 256) sdata[t] += add;
            __syncthreads();
        }
        if (t < 256) {
            const int excl = (t > 0) ? sdata[t - 1] : 0;
            const int n = (b << 8) + t;
            if (n < N) {
                rowstart[n] = base + excl;
                rowcnt[n]   = cnt[t];
            }
            cur[t] = base + excl;
        }
        __syncthreads();

        for (int i = base + t; i < endp; i += 1024) {
            const unsigned int v = packed[i];
            const int pos = atomicAdd(&cur[v >> SRC_BITS], 1);
            edge_src[pos] = (int)(v & SRC_MASK);
        }
        __syncthreads();
    }
}

// ---------------------------------------------------------------------------
// agg1 fused — DIAGNOSTIC x6 reps (idempotent).
// ---------------------------------------------------------------------------
__global__ __launch_bounds__(256) void agg1_fused_kernel(
    const unsigned short* __restrict__ hn1b, const float* __restrict__ hs1,
    const int* __restrict__ rowstart, const int* __restrict__ rowcnt,
    const int* __restrict__ edge_src,
    const float* __restrict__ Wn2, const float* __restrict__ Ws2,
    const float* __restrict__ b2,
    unsigned short* __restrict__ hn2b, float* __restrict__ hs2, int N)
{
    __shared__ float w2[16][33];
    __shared__ float bb[8];
    __shared__ float hsm[16][33];

    const int tid = threadIdx.x;
    const int g   = tid >> 4;
    const int ln  = tid & 15;

    const unsigned int* hn1u = (const unsigned int*)hn1b;
    const int n = blockIdx.x * 16 + g;

    for (int rep = 0; rep < REPS_A1; ++rep) {
        asm volatile("" ::: "memory");

        w2[tid >> 5][tid & 31]       = Wn2[tid];
        w2[8 + (tid >> 5)][tid & 31] = Ws2[tid];
        if (tid < 8) bb[tid] = b2[tid];

        float sx = 0.f, sy = 0.f;
        int degi = 0;
        if (n < N) {
            const int rs = rowstart[n];
            degi = rowcnt[n];
            const int re = rs + degi;
            int e = rs;
            for (; e + 8 <= re; e += 8) {
                const int s0 = edge_src[e + 0];
                const int s1 = edge_src[e + 1];
                const int s2 = edge_src[e + 2];
                const int s3 = edge_src[e + 3];
                const int s4 = edge_src[e + 4];
                const int s5 = edge_src[e + 5];
                const int s6 = edge_src[e + 6];
                const int s7 = edge_src[e + 7];
                const unsigned int v0 = hn1u[(size_t)s0 * 16 + ln];
                const unsigned int v1 = hn1u[(size_t)s1 * 16 + ln];
                const unsigned int v2 = hn1u[(size_t)s2 * 16 + ln];
                const unsigned int v3 = hn1u[(size_t)s3 * 16 + ln];
                const unsigned int v4 = hn1u[(size_t)s4 * 16 + ln];
                const unsigned int v5 = hn1u[(size_t)s5 * 16 + ln];
                const unsigned int v6 = hn1u[(size_t)s6 * 16 + ln];
                const unsigned int v7 = hn1u[(size_t)s7 * 16 + ln];
                sx += ((bflo(v0) + bflo(v1)) + (bflo(v2) + bflo(v3)))
                    + ((bflo(v4) + bflo(v5)) + (bflo(v6) + bflo(v7)));
                sy += ((bfhi(v0) + bfhi(v1)) + (bfhi(v2) + bfhi(v3)))
                    + ((bfhi(v4) + bfhi(v5)) + (bfhi(v6) + bfhi(v7)));
            }
            for (; e < re; ++e) {
                const unsigned int v = hn1u[(size_t)edge_src[e] * 16 + ln];
                sx += bflo(v); sy += bfhi(v);
            }
            const float inv = 1.0f / fmaxf((float)degi, 1.0f);
            const float2 hs = *(const float2*)(hs1 + (size_t)n * 32 + 2 * ln);
            hsm[g][2 * ln + 0] = fmaxf(hs.x + sx * inv, 0.0f);
            hsm[g][2 * ln + 1] = fmaxf(hs.y + sy * inv, 0.0f);
        }
        __syncthreads();

        if (n < N) {
            const float* wrow = w2[ln];
            const float* hv   = hsm[g];
            float acc = 0.0f;
#pragma unroll
            for (int k = 0; k < 32; ++k) acc += wrow[k] * hv[k];
            if (ln < 8) hn2b[(size_t)n * 8 + ln] = f2bf(acc);
            else        hs2[(size_t)n * 8 + (ln - 8)] = acc + bb[ln - 8];
        }
        __syncthreads();
    }
}

// ---------------------------------------------------------------------------
// agg2 fused (single pass, unchanged)
// ---------------------------------------------------------------------------
__global__ __launch_bounds__(256) void agg2_fused_kernel(
    const unsigned short* __restrict__ hn2b, const float* __restrict__ hs2,
    const int* __restrict__ rowstart, const int* __restrict__ rowcnt,
    const int* __restrict__ edge_src,
    float* __restrict__ out, int N)
{
    const int tid  = threadIdx.x;
    const int g    = tid >> 4;
    const int ln   = tid & 15;
    const int slot = ln >> 2;
    const int q    = ln & 3;

    const unsigned int* hn2u = (const unsigned int*)hn2b;

    const int n = blockIdx.x * 16 + g;
    float sx = 0.f, sy = 0.f;
    int degi = 0;
    if (n < N) {
        const int rs = rowstart[n];
        degi = rowcnt[n];
        const int re = rs + degi;
        for (int e = rs + slot; e < re; e += 4) {
            const unsigned int v = hn2u[(size_t)edge_src[e] * 4 + q];
            sx += bflo(v); sy += bfhi(v);
        }
    }
    sx += __shfl_xor(sx, 4, 64);  sy += __shfl_xor(sy, 4, 64);
    sx += __shfl_xor(sx, 8, 64);  sy += __shfl_xor(sy, 8, 64);

    if (n < N && slot == 0) {
        const float inv = 1.0f / fmaxf((float)degi, 1.0f);
        const float2 s = *(const float2*)(hs2 + (size_t)n * 8 + 2 * q);
        float2 o;
        o.x = s.x + sx * inv;
        o.y = s.y + sy * inv;
        *(float2*)(out + (size_t)n * 8 + 2 * q) = o;
    }
}

extern "C" void kernel_launch(void* const* d_in, const int* in_sizes, int n_in,
                              void* d_out, int out_size, void* d_ws, size_t ws_size,
                              hipStream_t stream)
{
    const float* feats = (const float*)d_in[0];
    const int*   src   = (const int*)d_in[1];
    const int*   dst   = (const int*)d_in[2];
    const float* Ws1   = (const float*)d_in[3];
    const float* Wn1   = (const float*)d_in[4];
    const float* b1    = (const float*)d_in[5];
    const float* Ws2   = (const float*)d_in[6];
    const float* Wn2   = (const float*)d_in[7];
    const float* b2    = (const float*)d_in[8];
    float* out = (float*)d_out;

    const int N  = in_sizes[0] / IN_FEATS;   // 100000
    const int E  = in_sizes[1];              // 3200000
    const int NB = (N + 255) >> 8;           // 391
    const int CAP = (int)((((2LL * E) / NB) + 255) & ~255LL);   // 16384

    // Workspace layout
    char* ws = (char*)d_ws;
    const size_t N32 = (size_t)N * 32;
    const size_t N8  = (size_t)N * 8;
    unsigned short* hn1b = (unsigned short*)ws;            // [N,32] bf16
    ws += ((N32 * 2 + 255) / 256) * 256;
    float* hs1 = (float*)ws;                               // [N,32] f32
    ws += ((N32 * 4 + 255) / 256) * 256;
    unsigned short* hn2b = (unsigned short*)ws;            // [N,8] bf16
    ws += ((N8 * 2 + 255) / 256) * 256;
    float* hs2 = (float*)ws;                               // [N,8] f32
    ws += ((N8 * 4 + 255) / 256) * 256;
    int* rowstart = (int*)ws;                              // [N]
    ws += (((size_t)N * 4 + 255) / 256) * 256;
    int* rowcnt = (int*)ws;                                // [N]
    ws += (((size_t)N * 4 + 255) / 256) * 256;
    int* bcursor = (int*)ws;                               // [512 * REPS_P]
    ws += 512 * REPS_P * 4;
    unsigned int* packed = (unsigned int*)ws;              // [NB*CAP]
    ws += (((size_t)NB * CAP * 4 + 255) / 256) * 256;
    unsigned int* packed_scratch = (unsigned int*)ws;      // [NB*CAP] (diag)
    ws += (((size_t)NB * CAP * 4 + 255) / 256) * 256;
    int* edge_src = (int*)ws;                              // [NB*CAP]

    const int nbPart = (E + PART_CHUNK - 1) / PART_CHUNK;

    init_cursor_kernel<<<1, 512, 0, stream>>>(bcursor, NB, CAP);
    partition_kernel<<<nbPart, 256, 0, stream>>>(src, dst, bcursor, packed,
                                                 packed_scratch, NB, E, CAP);
    csr_finalize_kernel<<<NB, 1024, 0, stream>>>(
        packed, bcursor + (REPS_P - 1) * 512, rowstart, rowcnt, edge_src, N, CAP);

    gemm1_kernel<<<(N + 63) / 64, 256, 0, stream>>>(feats, Wn1, Ws1, b1,
                                                    hn1b, hs1, N);

    agg1_fused_kernel<<<(N + 15) / 16, 256, 0, stream>>>(
        hn1b, hs1, rowstart, rowcnt, edge_src, Wn2, Ws2, b2, hn2b, hs2, N);

    agg2_fused_kernel<<<(N + 15) / 16, 256, 0, stream>>>(
        hn2b, hs2, rowstart, rowcnt, edge_src, out, N);
}

// Round 12
// 239.297 us; speedup vs baseline: 4.4523x; 4.4523x over previous
//
#include <hip/hip_runtime.h>
#include <hip/hip_bf16.h>

#define IN_FEATS 768
#define PART_CHUNK 8192
#define SRC_BITS 17
#define SRC_MASK 0x1FFFF

typedef __attribute__((ext_vector_type(8))) short short8v;
typedef __attribute__((ext_vector_type(4))) float f32x4;

__device__ __forceinline__ unsigned short f2bf(float f) {
    union { float f; unsigned int u; } c; c.f = f;
    unsigned int r = (c.u + 0x7FFFu + ((c.u >> 16) & 1u)) >> 16;  // RNE
    return (unsigned short)r;
}
__device__ __forceinline__ float bflo(unsigned int v) {
    union { unsigned int u; float f; } c; c.u = v << 16; return c.f;
}
__device__ __forceinline__ float bfhi(unsigned int v) {
    union { unsigned int u; float f; } c; c.u = v & 0xFFFF0000u; return c.f;
}
__device__ __forceinline__ short8v pack8(float4 p, float4 q) {
    short8v r;
    r[0] = (short)f2bf(p.x); r[1] = (short)f2bf(p.y);
    r[2] = (short)f2bf(p.z); r[3] = (short)f2bf(p.w);
    r[4] = (short)f2bf(q.x); r[5] = (short)f2bf(q.y);
    r[6] = (short)f2bf(q.z); r[7] = (short)f2bf(q.w);
    return r;
}

// ---------------------------------------------------------------------------
// init cursor: bcursor[b] = b*CAP
// ---------------------------------------------------------------------------
__global__ __launch_bounds__(512) void init_cursor_kernel(
    int* __restrict__ bcursor, int NB, int CAP)
{
    const int t = threadIdx.x;
    if (t < NB) bcursor[t] = t * CAP;
}

// ---------------------------------------------------------------------------
// FUSED kernel: blocks [0, nbPart) run the edge partition; blocks
// [nbPart, nbPart+nbGemm) run the layer-1 bf16-MFMA GEMM (v2 layout — r11
// measured v2 63.5us vs swizzled-v3 76us: kernel is latency-bound, conflicts
// are hidden, swizzle VALU cost is not). The two roles are data-independent;
// running them in one dispatch hides partition (~22us) in gemm's latency
// bubbles and removes a launch gap.
// GEMM: hn1b written as TWO feature halves [2][N][16] so agg1's gather table
// per pass is 3.2MB (< 4MB per-XCD L2).
// ---------------------------------------------------------------------------
__global__ __launch_bounds__(256) void gemm_part_kernel(
    const float* __restrict__ x,
    const float* __restrict__ Wn,
    const float* __restrict__ Ws,
    const float* __restrict__ b1,
    unsigned short* __restrict__ hn1b,   // [2][N][16] bf16 halves
    float* __restrict__ hs1,             // [N,32]
    int N,
    const int* __restrict__ src, const int* __restrict__ dst,
    int* __restrict__ bcursor, unsigned int* __restrict__ packed,
    int NB, int E, int CAP, int nbPart)
{
    __shared__ __align__(16) unsigned char smem[36864];
    const int tid = threadIdx.x;

    if ((int)blockIdx.x < nbPart) {
        // ================= partition role =================
        int* hcnt  = (int*)smem;         // [512]
        int* hbase = hcnt + 512;         // [512]

        for (int i = tid; i < NB; i += 256) hcnt[i] = 0;
        __syncthreads();

        const int start = blockIdx.x * PART_CHUNK;
        const int end   = min(start + PART_CHUNK, E);
        const int vend  = start + ((end - start) & ~3);

        for (int i = start + tid * 4; i + 3 < end; i += 1024) {
            const int4 d4 = *(const int4*)&dst[i];
            atomicAdd(&hcnt[d4.x >> 8], 1);
            atomicAdd(&hcnt[d4.y >> 8], 1);
            atomicAdd(&hcnt[d4.z >> 8], 1);
            atomicAdd(&hcnt[d4.w >> 8], 1);
        }
        for (int i = vend + tid; i < end; i += 256)
            atomicAdd(&hcnt[dst[i] >> 8], 1);
        __syncthreads();

        for (int i = tid; i < NB; i += 256) {
            const int c = hcnt[i];
            hbase[i] = c ? atomicAdd(&bcursor[i], c) : 0;
            hcnt[i] = 0;
        }
        __syncthreads();

        for (int i = start + tid * 4; i + 3 < end; i += 1024) {
            const int4 d4 = *(const int4*)&dst[i];
            const int4 s4 = *(const int4*)&src[i];
            {
                const int b = d4.x >> 8;
                const int p = hbase[b] + atomicAdd(&hcnt[b], 1);
                if (p < (b + 1) * CAP) packed[p] = ((unsigned int)(d4.x & 255) << SRC_BITS) | (unsigned int)s4.x;
            }
            {
                const int b = d4.y >> 8;
                const int p = hbase[b] + atomicAdd(&hcnt[b], 1);
                if (p < (b + 1) * CAP) packed[p] = ((unsigned int)(d4.y & 255) << SRC_BITS) | (unsigned int)s4.y;
            }
            {
                const int b = d4.z >> 8;
                const int p = hbase[b] + atomicAdd(&hcnt[b], 1);
                if (p < (b + 1) * CAP) packed[p] = ((unsigned int)(d4.z & 255) << SRC_BITS) | (unsigned int)s4.z;
            }
            {
                const int b = d4.w >> 8;
                const int p = hbase[b] + atomicAdd(&hcnt[b], 1);
                if (p < (b + 1) * CAP) packed[p] = ((unsigned int)(d4.w & 255) << SRC_BITS) | (unsigned int)s4.w;
            }
        }
        for (int i = vend + tid; i < end; i += 256) {
            const int d = dst[i];
            const int b = d >> 8;
            const int p = hbase[b] + atomicAdd(&hcnt[b], 1);
            if (p < (b + 1) * CAP) packed[p] = ((unsigned int)(d & 255) << SRC_BITS) | (unsigned int)src[i];
        }
        return;
    }

    // ================= gemm role (v2: [2][64][72], one barrier/step) =======
    unsigned short* AsB = (unsigned short*)smem;          // [2][64][72]
    unsigned short* BsB = AsB + 2 * 64 * 72;              // [2][64][72]
#define AS(b, r) (AsB + ((b) * 64 + (r)) * 72)
#define BS(b, r) (BsB + ((b) * 64 + (r)) * 72)

    const int lrow = tid >> 2;          // staging row 0..63
    const int lk16 = (tid & 3) * 16;    // staging k-offset
    const int row0 = ((int)blockIdx.x - nbPart) * 64;

    const int  grow   = row0 + lrow;
    const bool rvalid = (grow < N);
    const float* xrow = x + (size_t)(rvalid ? grow : (N - 1)) * IN_FEATS;
    const float* wrow = (lrow < 32) ? (Wn + (size_t)lrow * IN_FEATS)
                                    : (Ws + (size_t)(lrow - 32) * IN_FEATS);

    const int w    = tid >> 6;
    const int l    = tid & 63;
    const int lr16 = l & 15;
    const int lk   = (l >> 4) * 8;

    f32x4 acc[4];
#pragma unroll
    for (int ct = 0; ct < 4; ++ct) acc[ct] = (f32x4){0.f, 0.f, 0.f, 0.f};

    float4 a0, a1, a2, a3, w0, w1, w2, w3;
    a0 = *(const float4*)(xrow + lk16 + 0);
    a1 = *(const float4*)(xrow + lk16 + 4);
    a2 = *(const float4*)(xrow + lk16 + 8);
    a3 = *(const float4*)(xrow + lk16 + 12);
    w0 = *(const float4*)(wrow + lk16 + 0);
    w1 = *(const float4*)(wrow + lk16 + 4);
    w2 = *(const float4*)(wrow + lk16 + 8);
    w3 = *(const float4*)(wrow + lk16 + 12);

    const int NSTEP = IN_FEATS / 64;    // 12
    for (int step = 0; step < NSTEP; ++step) {
        const int buf = step & 1;
        *(short8v*)(AS(buf, lrow) + lk16)     = pack8(a0, a1);
        *(short8v*)(AS(buf, lrow) + lk16 + 8) = pack8(a2, a3);
        *(short8v*)(BS(buf, lrow) + lk16)     = pack8(w0, w1);
        *(short8v*)(BS(buf, lrow) + lk16 + 8) = pack8(w2, w3);
        __syncthreads();

        if (step + 1 < NSTEP) {
            const int k0 = (step + 1) * 64;
            a0 = *(const float4*)(xrow + k0 + lk16 + 0);
            a1 = *(const float4*)(xrow + k0 + lk16 + 4);
            a2 = *(const float4*)(xrow + k0 + lk16 + 8);
            a3 = *(const float4*)(xrow + k0 + lk16 + 12);
            w0 = *(const float4*)(wrow + k0 + lk16 + 0);
            w1 = *(const float4*)(wrow + k0 + lk16 + 4);
            w2 = *(const float4*)(wrow + k0 + lk16 + 8);
            w3 = *(const float4*)(wrow + k0 + lk16 + 12);
        }

        short8v af0 = *(const short8v*)(AS(buf, w * 16 + lr16) + lk);
        short8v af1 = *(const short8v*)(AS(buf, w * 16 + lr16) + lk + 32);
#pragma unroll
        for (int ct = 0; ct < 4; ++ct) {
            short8v bf0 = *(const short8v*)(BS(buf, ct * 16 + lr16) + lk);
            acc[ct] = __builtin_amdgcn_mfma_f32_16x16x32_bf16(af0, bf0, acc[ct], 0, 0, 0);
        }
#pragma unroll
        for (int ct = 0; ct < 4; ++ct) {
            short8v bf1 = *(const short8v*)(BS(buf, ct * 16 + lr16) + lk + 32);
            acc[ct] = __builtin_amdgcn_mfma_f32_16x16x32_bf16(af1, bf1, acc[ct], 0, 0, 0);
        }
    }
#undef AS
#undef BS

    // epilogue: D layout col=lane&15, row=(lane>>4)*4+reg.
    // hn1 cols go to feature-half layout [2][N][16].
    const int rbase = row0 + w * 16 + (l >> 4) * 4;
#pragma unroll
    for (int ct = 0; ct < 4; ++ct) {
        const int ncol = ct * 16 + lr16;
        if (ncol < 32) {
            const int half = ncol >> 4;
            const int c16  = ncol & 15;
            unsigned short* hd = hn1b + (size_t)half * N * 16;
#pragma unroll
            for (int j = 0; j < 4; ++j) {
                const int r = rbase + j;
                if (r < N) hd[(size_t)r * 16 + c16] = f2bf(acc[ct][j]);
            }
        } else {
            const int c = ncol - 32;
            const float bias = b1[c];
#pragma unroll
            for (int j = 0; j < 4; ++j) {
                const int r = rbase + j;
                if (r < N) hs1[(size_t)r * 32 + c] = acc[ct][j] + bias;
            }
        }
    }
}

// ---------------------------------------------------------------------------
// Per-bucket CSR finalize (unchanged from round 10).
// ---------------------------------------------------------------------------
__global__ __launch_bounds__(1024) void csr_finalize_kernel(
    const unsigned int* __restrict__ packed, const int* __restrict__ bcursor,
    int* __restrict__ rowstart, int* __restrict__ rowcnt,
    int* __restrict__ edge_src, int N, int CAP)
{
    __shared__ int cnt[256];
    __shared__ int sdata[256];
    __shared__ int cur[256];
    const int b = blockIdx.x;
    const int t = threadIdx.x;
    const int base = b * CAP;
    const int endp = min(bcursor[b], base + CAP);

    if (t < 256) cnt[t] = 0;
    __syncthreads();
    for (int i = base + t; i < endp; i += 1024)
        atomicAdd(&cnt[packed[i] >> SRC_BITS], 1);
    __syncthreads();

    if (t < 256) sdata[t] = cnt[t];
    __syncthreads();
    for (int off = 1; off < 256; off <<= 1) {
        const int add = (t < 256 && t >= off) ? sdata[t - off] : 0;
        __syncthreads();
        if (t < 256) sdata[t] += add;
        __syncthreads();
    }
    if (t < 256) {
        const int excl = (t > 0) ? sdata[t - 1] : 0;
        const int n = (b << 8) + t;
        if (n < N) {
            rowstart[n] = base + excl;
            rowcnt[n]   = cnt[t];
        }
        cur[t] = base + excl;
    }
    __syncthreads();

    for (int i = base + t; i < endp; i += 1024) {
        const unsigned int v = packed[i];
        const int pos = atomicAdd(&cur[v >> SRC_BITS], 1);
        edge_src[pos] = (int)(v & SRC_MASK);
    }
}

// ---------------------------------------------------------------------------
// agg1 fused v2: TWO passes over feature halves so the gather table per pass
// is 3.2MB (L2-resident; r7 measured 102MB HBM refetch with the 6.4MB table).
// 32 nodes/block x 8 lanes; deg comes from rowcnt (no counting).
// ---------------------------------------------------------------------------
__global__ __launch_bounds__(256) void agg1_fused_kernel(
    const unsigned short* __restrict__ hn1b,   // [2][N][16] halves
    const float* __restrict__ hs1,             // [N,32]
    const int* __restrict__ rowstart, const int* __restrict__ rowcnt,
    const int* __restrict__ edge_src,
    const float* __restrict__ Wn2, const float* __restrict__ Ws2,
    const float* __restrict__ b2,
    unsigned short* __restrict__ hn2b, float* __restrict__ hs2, int N)
{
    __shared__ float w2[16][33];
    __shared__ float bb[8];
    __shared__ float hsm[32][33];

    const int tid = threadIdx.x;
    const int g   = tid >> 3;      // node slot 0..31
    const int ln  = tid & 7;       // pair lane 0..7

    w2[tid >> 5][tid & 31]       = Wn2[tid];
    w2[8 + (tid >> 5)][tid & 31] = Ws2[tid];
    if (tid < 8) bb[tid] = b2[tid];

    const int n = blockIdx.x * 32 + g;
    int rs = 0, degi = 0;
    if (n < N) { rs = rowstart[n]; degi = rowcnt[n]; }
    const float inv = 1.0f / fmaxf((float)degi, 1.0f);
    const int re = rs + degi;

#pragma unroll
    for (int h = 0; h < 2; ++h) {
        const unsigned int* tab = (const unsigned int*)hn1b + (size_t)h * N * 8;
        float sx = 0.f, sy = 0.f;
        if (n < N) {
            int e = rs;
            for (; e + 4 <= re; e += 4) {
                const int s0 = edge_src[e + 0];
                const int s1 = edge_src[e + 1];
                const int s2 = edge_src[e + 2];
                const int s3 = edge_src[e + 3];
                const unsigned int v0 = tab[(size_t)s0 * 8 + ln];
                const unsigned int v1 = tab[(size_t)s1 * 8 + ln];
                const unsigned int v2 = tab[(size_t)s2 * 8 + ln];
                const unsigned int v3 = tab[(size_t)s3 * 8 + ln];
                sx += (bflo(v0) + bflo(v1)) + (bflo(v2) + bflo(v3));
                sy += (bfhi(v0) + bfhi(v1)) + (bfhi(v2) + bfhi(v3));
            }
            for (; e < re; ++e) {
                const unsigned int v = tab[(size_t)edge_src[e] * 8 + ln];
                sx += bflo(v); sy += bfhi(v);
            }
            const int f = h * 16 + 2 * ln;
            const float2 hsv = *(const float2*)(hs1 + (size_t)n * 32 + f);
            hsm[g][f + 0] = fmaxf(hsv.x + sx * inv, 0.0f);
            hsm[g][f + 1] = fmaxf(hsv.y + sy * inv, 0.0f);
        }
    }
    __syncthreads();

    // layer-2 linears: 32 nodes x 16 outputs over 256 threads (2 rounds)
    if (n < N) {
        const float* hv = hsm[g];
#pragma unroll
        for (int o2 = 0; o2 < 2; ++o2) {
            const int o = o2 * 8 + ln;
            const float* wr = w2[o];
            float acc = 0.0f;
#pragma unroll
            for (int k = 0; k < 32; ++k) acc += wr[k] * hv[k];
            if (o < 8) hn2b[(size_t)n * 8 + o] = f2bf(acc);
            else       hs2[(size_t)n * 8 + (o - 8)] = acc + bb[o - 8];
        }
    }
}

// ---------------------------------------------------------------------------
// agg2 fused (unchanged from round 10).
// ---------------------------------------------------------------------------
__global__ __launch_bounds__(256) void agg2_fused_kernel(
    const unsigned short* __restrict__ hn2b, const float* __restrict__ hs2,
    const int* __restrict__ rowstart, const int* __restrict__ rowcnt,
    const int* __restrict__ edge_src,
    float* __restrict__ out, int N)
{
    const int tid  = threadIdx.x;
    const int g    = tid >> 4;
    const int ln   = tid & 15;
    const int slot = ln >> 2;
    const int q    = ln & 3;

    const unsigned int* hn2u = (const unsigned int*)hn2b;

    const int n = blockIdx.x * 16 + g;
    float sx = 0.f, sy = 0.f;
    int degi = 0;
    if (n < N) {
        const int rs = rowstart[n];
        degi = rowcnt[n];
        const int re = rs + degi;
        for (int e = rs + slot; e < re; e += 4) {
            const unsigned int v = hn2u[(size_t)edge_src[e] * 4 + q];
            sx += bflo(v); sy += bfhi(v);
        }
    }
    sx += __shfl_xor(sx, 4, 64);  sy += __shfl_xor(sy, 4, 64);
    sx += __shfl_xor(sx, 8, 64);  sy += __shfl_xor(sy, 8, 64);

    if (n < N && slot == 0) {
        const float inv = 1.0f / fmaxf((float)degi, 1.0f);
        const float2 s = *(const float2*)(hs2 + (size_t)n * 8 + 2 * q);
        float2 o;
        o.x = s.x + sx * inv;
        o.y = s.y + sy * inv;
        *(float2*)(out + (size_t)n * 8 + 2 * q) = o;
    }
}

extern "C" void kernel_launch(void* const* d_in, const int* in_sizes, int n_in,
                              void* d_out, int out_size, void* d_ws, size_t ws_size,
                              hipStream_t stream)
{
    const float* feats = (const float*)d_in[0];
    const int*   src   = (const int*)d_in[1];
    const int*   dst   = (const int*)d_in[2];
    const float* Ws1   = (const float*)d_in[3];
    const float* Wn1   = (const float*)d_in[4];
    const float* b1    = (const float*)d_in[5];
    const float* Ws2   = (const float*)d_in[6];
    const float* Wn2   = (const float*)d_in[7];
    const float* b2    = (const float*)d_in[8];
    float* out = (float*)d_out;

    const int N  = in_sizes[0] / IN_FEATS;   // 100000
    const int E  = in_sizes[1];              // 3200000
    const int NB = (N + 255) >> 8;           // 391
    const int CAP = (int)((((2LL * E) / NB) + 255) & ~255LL);   // 16384

    // Workspace layout
    char* ws = (char*)d_ws;
    const size_t N32 = (size_t)N * 32;
    const size_t N8  = (size_t)N * 8;
    unsigned short* hn1b = (unsigned short*)ws;            // [2][N][16] bf16
    ws += ((N32 * 2 + 255) / 256) * 256;
    float* hs1 = (float*)ws;                               // [N,32] f32
    ws += ((N32 * 4 + 255) / 256) * 256;
    unsigned short* hn2b = (unsigned short*)ws;            // [N,8] bf16
    ws += ((N8 * 2 + 255) / 256) * 256;
    float* hs2 = (float*)ws;                               // [N,8] f32
    ws += ((N8 * 4 + 255) / 256) * 256;
    int* rowstart = (int*)ws;                              // [N]
    ws += (((size_t)N * 4 + 255) / 256) * 256;
    int* rowcnt = (int*)ws;                                // [N]
    ws += (((size_t)N * 4 + 255) / 256) * 256;
    int* bcursor = (int*)ws;                               // [512]
    ws += 512 * 4;
    unsigned int* packed = (unsigned int*)ws;              // [NB*CAP]
    ws += (((size_t)NB * CAP * 4 + 255) / 256) * 256;
    int* edge_src = (int*)ws;                              // [NB*CAP]

    const int nbPart = (E + PART_CHUNK - 1) / PART_CHUNK;  // 391
    const int nbGemm = (N + 63) / 64;                      // 1563

    // 1) cursor init
    init_cursor_kernel<<<1, 512, 0, stream>>>(bcursor, NB, CAP);

    // 2) FUSED: edge partition (blocks 0..nbPart) || layer-1 GEMM (rest)
    gemm_part_kernel<<<nbPart + nbGemm, 256, 0, stream>>>(
        feats, Wn1, Ws1, b1, hn1b, hs1, N,
        src, dst, bcursor, packed, NB, E, CAP, nbPart);

    // 3) per-bucket CSR finalize
    csr_finalize_kernel<<<NB, 1024, 0, stream>>>(packed, bcursor, rowstart,
                                                 rowcnt, edge_src, N, CAP);

    // 4) layer-1 aggregation (two L2-resident half passes) + layer-2 linear
    agg1_fused_kernel<<<(N + 31) / 32, 256, 0, stream>>>(
        hn1b, hs1, rowstart, rowcnt, edge_src, Wn2, Ws2, b2, hn2b, hs2, N);

    // 5) layer-2 aggregation + final combine
    agg2_fused_kernel<<<(N + 15) / 16, 256, 0, stream>>>(
        hn2b, hs2, rowstart, rowcnt, edge_src, out, N);
}